// Round 2
// baseline (2528.800 us; speedup 1.0000x reference)
//
#include <hip/hip_runtime.h>
#include <math.h>

#define NNODES 20000
#define NEDGES 100000
#define DN 1280
#define DE 505
#define NH 20
#define NQ 2560      // Q gemm N (= 2*DN)
#define KQ 1280      // Q gemm K
#define MQP 20096    // 157*128 padded nodes
#define KE 512       // padded edge-K (505 -> 512)
#define MEP 100096   // 782*128 padded edges

// d_out float offsets: h[25.6M], edge_core[50.5M], global_fea[1280], att[2M]
#define OUT_EC  25600000ull
#define OUT_GF  76100000ull
#define OUT_ATT 76101280ull

// workspace byte offsets
#define WS_HB   0ull                 // u16[MQP*KQ]
#define WS_ECB  51445760ull          // u16[MEP*KE]
#define WS_WQT  153944064ull         // u16[NQ*KQ]   (B^T for Q gemm)
#define WS_WMT  160497664ull         // u16[DN*KE]   (B^T for EC gemm)
#define WS_QB   161808384ull         // u16[MQP*NQ]  (node projections, bf16)
#define WS_EXPW 264699904ull         // f32[NEDGES*NH]
#define WS_P    272699904ull         // f32[NNODES*40]
#define WS_S    275899904ull         // f32[20]
#define WS_GF   275900160ull         // f32[1280]
#define WS_Y1   275905280ull         // f32[5120]
#define WS_Z    275925760ull         // f32[1280]
#define WS_GO   275930880ull         // f32[1280]
#define WS_ZERO_FLOATS 9024          // zero span from WS_S

typedef unsigned short u16;
typedef __attribute__((ext_vector_type(8))) short bf16x8;
typedef __attribute__((ext_vector_type(4))) float f32x4;
typedef __attribute__((ext_vector_type(4))) unsigned short us4;
typedef __attribute__((ext_vector_type(8))) unsigned short us8;
typedef __attribute__((ext_vector_type(4))) float fl4;

__device__ __forceinline__ float bf2f(u16 u){ union{unsigned v; float f;} x; x.v = ((unsigned)u)<<16; return x.f; }
__device__ __forceinline__ u16 f2bf(float f){ union{float f; unsigned v;} x; x.f=f; unsigned r = x.v + 0x7FFFu + ((x.v>>16)&1u); return (u16)(r>>16); }

#define GLD16(gp, lp) __builtin_amdgcn_global_load_lds((const __attribute__((address_space(1))) void*)(gp), (__attribute__((address_space(3))) void*)(lp), 16, 0, 0)

__global__ void k_init(float* z){
  int i = blockIdx.x*blockDim.x + threadIdx.x;
  if (i < WS_ZERO_FLOATS) z[i] = 0.f;
}

// h -> bf16 padded [MQP][DN], and copy h -> out
__global__ void k_prep_h(const float* __restrict__ h, u16* __restrict__ hb, float* __restrict__ outh){
  const size_t total = (size_t)MQP*DN/4;
  const size_t lim = (size_t)NNODES*DN/4;
  size_t stride = (size_t)gridDim.x*blockDim.x;
  for (size_t i = (size_t)blockIdx.x*blockDim.x + threadIdx.x; i < total; i += stride){
    fl4 v = {0.f,0.f,0.f,0.f};
    if (i < lim){ v = *(const fl4*)(h + i*4); *(fl4*)(outh + i*4) = v; }
    us4 b; b[0]=f2bf(v[0]); b[1]=f2bf(v[1]); b[2]=f2bf(v[2]); b[3]=f2bf(v[3]);
    *(us4*)(hb + i*4) = b;
  }
}

// edge_core -> bf16 padded [MEP][KE], and copy edge_core -> out
__global__ void k_prep_ec(const float* __restrict__ ec, u16* __restrict__ ecb, float* __restrict__ outec){
  size_t stride = (size_t)gridDim.x*blockDim.x;
  size_t tid = (size_t)blockIdx.x*blockDim.x + threadIdx.x;
  const size_t itemsA = (size_t)MEP*64;
  for (size_t i = tid; i < itemsA; i += stride){
    int e = (int)(i>>6); int k0 = (int)(i&63)<<3;
    us8 b;
    #pragma unroll
    for (int tt=0; tt<8; tt++){
      int k = k0+tt;
      float v = (e < NEDGES && k < DE) ? ec[(size_t)e*DE + k] : 0.f;
      b[tt] = f2bf(v);
    }
    *(us8*)(ecb + ((size_t)e<<9) + k0) = b;
  }
  const size_t itemsB = (size_t)NEDGES*DE/4;
  for (size_t i = tid; i < itemsB; i += stride)
    *(fl4*)(outec + i*4) = *(const fl4*)(ec + i*4);
}

// W_node -> B^T bf16 blocks: wqt[c][k] (c<1280: top rows, else bottom rows), wmt[c][kk] (mid rows, k-padded)
__global__ void k_prep_w(const float* __restrict__ Wn, u16* __restrict__ wqt, u16* __restrict__ wmt){
  size_t stride = (size_t)gridDim.x*blockDim.x;
  size_t tid = (size_t)blockIdx.x*blockDim.x + threadIdx.x;
  for (size_t i = tid; i < (size_t)KQ*NQ; i += stride){
    int k = (int)(i / NQ); int c = (int)(i % NQ);
    float v = (c < DN) ? Wn[(size_t)k*DN + c] : Wn[(size_t)(1785+k)*DN + (c-DN)];
    wqt[(size_t)c*KQ + k] = f2bf(v);
  }
  for (size_t i = tid; i < (size_t)DN*KE; i += stride){
    int kk = (int)(i & (KE-1)); int c = (int)(i >> 9);
    float v = (kk < DE) ? Wn[(size_t)(DN+kk)*DN + c] : 0.f;
    wmt[(size_t)c*KE + kk] = f2bf(v);
  }
}

// P[n][c]: c<20 -> h.Wa_top col c ; c>=20 -> h.Wa_bot col c-20   (fp32)
__global__ void k_P(const float* __restrict__ h, const float* __restrict__ Wa, float* __restrict__ P){
  int i = blockIdx.x*blockDim.x + threadIdx.x;
  if (i >= NNODES*40) return;
  int n = i / 40, c = i % 40;
  const float* hr = h + (size_t)n*DN;
  const float* wcol = (c < NH) ? (Wa + c) : (Wa + (size_t)1785*NH + (c-NH));
  float acc = 0.f;
  for (int k=0;k<DN;k++) acc += hr[k]*wcol[(size_t)k*NH];
  P[i] = acc;
}

// per-edge logits -> expw, and S[h] = sum exp (no max-sub: relu'd logits are >=0, tiny)
__global__ void k_w(const float* __restrict__ ec, const float* __restrict__ P,
                    const int* __restrict__ idx, const float* __restrict__ Wa,
                    const float* __restrict__ ba, float* __restrict__ expw, float* __restrict__ S){
  __shared__ float ssum[NH];
  int t = threadIdx.x;
  if (t < NH) ssum[t] = 0.f;
  __syncthreads();
  int i = blockIdx.x*blockDim.x + t;
  float ev = 0.f; int hh = 0;
  if (i < NEDGES*NH){
    int e = i / NH; hh = i % NH;
    int ii = idx[e], jj = idx[NEDGES+e];
    float acc = P[ii*40+hh] + P[jj*40+NH+hh] + ba[hh];
    const float* er = ec + (size_t)e*DE;
    const float* wc = Wa + (size_t)DN*NH + hh;
    for (int k=0;k<DE;k++) acc += er[k]*wc[(size_t)k*NH];
    float w = fmaxf(acc, 0.f)*0.125f;
    ev = expf(w);
    expw[i] = ev;
  }
  atomicAdd(&ssum[hh], ev);
  __syncthreads();
  if (t < NH) atomicAdd(&S[t], ssum[t]);
}

__global__ void k_att(const float* __restrict__ expw, const float* __restrict__ S, float* __restrict__ att){
  size_t stride = (size_t)gridDim.x*blockDim.x;
  for (size_t i = (size_t)blockIdx.x*blockDim.x + threadIdx.x; i < (size_t)NEDGES*NH; i += stride)
    att[i] = expw[i] / S[i % NH];
}

// m97-style bf16 MFMA GEMM, 128x128 tile, BK=32, 4 waves (2x2), B^T input.
// EPI=0: store bf16 to Qb.  EPI=1: fused gather(Q)+bias+gelu+att-weighted column reduce -> gf.
template<int KSTEPS, int EPI>
__global__ __launch_bounds__(256) void k_gemm(
    const u16* __restrict__ A, const u16* __restrict__ Bt, int K, int Ntiles,
    u16* __restrict__ Qb,
    const int* __restrict__ idx, const float* __restrict__ bnode,
    const float* __restrict__ att, float* __restrict__ gf)
{
  __shared__ u16 lsA[4096];
  __shared__ u16 lsB[4096];
  __shared__ float red[128];
  int t = threadIdx.x; int w = t>>6; int l = t&63;
  int bid = blockIdx.x;
  int mt = bid / Ntiles, nt = bid % Ntiles;
  size_t m0 = (size_t)mt*128; int n0 = nt*128;
  const u16* gA = A + (m0 + (size_t)(t>>2))*K + ((t&3)<<3);
  const u16* gB = Bt + ((size_t)n0 + (t>>2))*K + ((t&3)<<3);
  size_t skip = (size_t)64*K;
  u16* lA0 = lsA + w*512; u16* lA1 = lsA + 2048 + w*512;
  u16* lB0 = lsB + w*512; u16* lB1 = lsB + 2048 + w*512;
  f32x4 acc[4][4];
  #pragma unroll
  for (int a=0;a<4;a++)
    #pragma unroll
    for (int b=0;b<4;b++) acc[a][b] = 0.f;
  int wm = w>>1, wn = w&1;
  int lrow = l&15; int lkb = (l>>4)<<3;
  for (int ks=0; ks<KSTEPS; ks++){
    GLD16(gA, lA0); GLD16(gA+skip, lA1);
    GLD16(gB, lB0); GLD16(gB+skip, lB1);
    gA += 32; gB += 32;
    __syncthreads();
    bf16x8 af[4], bfv[4];
    #pragma unroll
    for (int f=0; f<4; f++) af[f] = *(const bf16x8*)(lsA + ((wm*64 + f*16 + lrow)<<5) + lkb);
    #pragma unroll
    for (int f=0; f<4; f++) bfv[f] = *(const bf16x8*)(lsB + ((wn*64 + f*16 + lrow)<<5) + lkb);
    #pragma unroll
    for (int fm=0; fm<4; fm++)
      #pragma unroll
      for (int fn=0; fn<4; fn++)
        acc[fm][fn] = __builtin_amdgcn_mfma_f32_16x16x32_bf16(af[fm], bfv[fn], acc[fm][fn], 0, 0, 0);
    __syncthreads();
  }
  int orow = wm*64 + ((l>>4)<<2);   // + fm*16 + r
  int ocol = wn*64 + lrow;          // + fn*16
  if (EPI == 0){
    #pragma unroll
    for (int fm=0; fm<4; fm++)
      #pragma unroll
      for (int fn=0; fn<4; fn++)
        #pragma unroll
        for (int r=0; r<4; r++)
          Qb[(m0 + orow + fm*16 + r)*(size_t)NQ + n0 + ocol + fn*16] = f2bf(acc[fm][fn][r]);
  } else {
    if (t < 128) red[t] = 0.f;
    __syncthreads();
    int iarr[16], jarr[16];
    #pragma unroll
    for (int fm=0; fm<4; fm++)
      #pragma unroll
      for (int r=0; r<4; r++){
        int e = (int)m0 + orow + fm*16 + r;
        bool vld = e < NEDGES;
        iarr[fm*4+r] = vld ? idx[e] : 0;
        jarr[fm*4+r] = vld ? idx[NEDGES + e] : 0;
      }
    #pragma unroll
    for (int fn=0; fn<4; fn++){
      int col = n0 + ocol + fn*16;   // global d in [0,1280)
      int hd = col >> 6;
      float bn = bnode[col];
      float csum = 0.f;
      #pragma unroll
      for (int fm=0; fm<4; fm++)
        #pragma unroll
        for (int r=0; r<4; r++){
          int e = (int)m0 + orow + fm*16 + r;
          if (e < NEDGES){
            float u = acc[fm][fn][r]
                    + bf2f(Qb[(size_t)iarr[fm*4+r]*NQ + col])
                    + bf2f(Qb[(size_t)jarr[fm*4+r]*NQ + DN + col])
                    + bn;
            float g = 0.5f*u*(1.f + erff(u*0.70710678118654752f));
            csum += att[(size_t)e*NH + hd] * g;
          }
        }
      atomicAdd(&red[ocol + fn*16], csum);
    }
    __syncthreads();
    if (t < 128) atomicAdd(&gf[n0 + t], red[t]);
  }
}

// FF: y1pre += gf@W1 chunk (+b1 on kc0); relu applied when read in ff2
__global__ void k_ff1(const float* __restrict__ gf, const float* __restrict__ W1,
                      const float* __restrict__ b1, float* __restrict__ y1pre){
  __shared__ float sg[320];
  int jc = blockIdx.x % 20, kc = blockIdx.x / 20;
  int j = jc*256 + threadIdx.x;
  int k0 = kc*320;
  for (int i=threadIdx.x; i<320; i+=256) sg[i] = gf[k0+i];
  __syncthreads();
  float acc = (kc==0) ? b1[j] : 0.f;
  for (int k=0;k<320;k++) acc += sg[k]*W1[(size_t)(k0+k)*5120 + j];
  atomicAdd(&y1pre[j], acc);
}

__global__ void k_ff2(const float* __restrict__ y1pre, const float* __restrict__ W2,
                      const float* __restrict__ b2, float* __restrict__ z){
  __shared__ float sy[640];
  int dc = blockIdx.x % 5, kc = blockIdx.x / 5;
  int d = dc*256 + threadIdx.x;
  int k0 = kc*640;
  for (int i=threadIdx.x; i<640; i+=256) sy[i] = fmaxf(y1pre[k0+i], 0.f);
  __syncthreads();
  float acc = (kc==0) ? b2[d] : 0.f;
  for (int k=0;k<640;k++) acc += sy[k]*W2[(size_t)(k0+k)*1280 + d];
  atomicAdd(&z[d], acc);
}

__global__ void k_ff3(const float* __restrict__ z, const float* __restrict__ Wh, float* __restrict__ go){
  __shared__ float sz[320];
  int dc = blockIdx.x % 5, kc = blockIdx.x / 5;
  int d = dc*256 + threadIdx.x;
  int k0 = kc*320;
  for (int i=threadIdx.x; i<320; i+=256) sz[i] = z[k0+i];
  __syncthreads();
  float acc = 0.f;
  for (int k=0;k<320;k++) acc += sz[k]*Wh[(size_t)(k0+k)*1280 + d];
  atomicAdd(&go[d], acc);
}

__global__ void k_final(const float* __restrict__ go, float* __restrict__ outgf){
  int d = blockIdx.x*blockDim.x + threadIdx.x;
  if (d < 1280) outgf[d] = go[d];
}

extern "C" void kernel_launch(void* const* d_in, const int* in_sizes, int n_in,
                              void* d_out, int out_size, void* d_ws, size_t ws_size,
                              hipStream_t stream){
  const float* h   = (const float*)d_in[0];
  const float* ec  = (const float*)d_in[1];
  const int*   idx = (const int*)d_in[2];   // harness delivers integer inputs as int32
  const float* Wa  = (const float*)d_in[3];
  const float* ba  = (const float*)d_in[4];
  const float* Wn  = (const float*)d_in[5];
  const float* bn  = (const float*)d_in[6];
  const float* W1  = (const float*)d_in[7];
  const float* b1  = (const float*)d_in[8];
  const float* W2  = (const float*)d_in[9];
  const float* b2  = (const float*)d_in[10];
  const float* Wh  = (const float*)d_in[11];
  float* out = (float*)d_out;
  char* ws = (char*)d_ws;
  u16* hb   = (u16*)(ws + WS_HB);
  u16* ecb  = (u16*)(ws + WS_ECB);
  u16* wqt  = (u16*)(ws + WS_WQT);
  u16* wmt  = (u16*)(ws + WS_WMT);
  u16* qb   = (u16*)(ws + WS_QB);
  float* expw = (float*)(ws + WS_EXPW);
  float* P    = (float*)(ws + WS_P);
  float* S    = (float*)(ws + WS_S);
  float* gfb  = (float*)(ws + WS_GF);
  float* y1   = (float*)(ws + WS_Y1);
  float* z    = (float*)(ws + WS_Z);
  float* go   = (float*)(ws + WS_GO);

  k_init<<<36,256,0,stream>>>(S);
  k_prep_h<<<2048,256,0,stream>>>(h, hb, out);
  k_prep_ec<<<3072,256,0,stream>>>(ec, ecb, out + OUT_EC);
  k_prep_w<<<2048,256,0,stream>>>(Wn, wqt, wmt);
  k_P<<<3125,256,0,stream>>>(h, Wa, P);
  k_w<<<7813,256,0,stream>>>(ec, P, idx, Wa, ba, expw, S);
  k_att<<<2048,256,0,stream>>>(expw, S, out + OUT_ATT);
  k_gemm<40,0><<<157*20,256,0,stream>>>(hb, wqt, KQ, 20, qb, nullptr, nullptr, nullptr, nullptr);
  k_gemm<16,1><<<782*10,256,0,stream>>>(ecb, wmt, KE, 10, qb, idx, bn, out + OUT_ATT, gfb);
  k_ff1<<<80,256,0,stream>>>(gfb, W1, b1, y1);
  k_ff2<<<40,256,0,stream>>>(y1, W2, b2, z);
  k_ff3<<<20,256,0,stream>>>(z, Wh, go);
  k_final<<<5,256,0,stream>>>(go, out + OUT_GF);
}

// Round 3
// 1900.031 us; speedup vs baseline: 1.3309x; 1.3309x over previous
//
#include <hip/hip_runtime.h>
#include <math.h>

#define NNODES 20000
#define NEDGES 100000
#define DN 1280
#define DE 505
#define NH 20
#define NQ 2560      // Q gemm N (= 2*DN)
#define KQ 1280      // Q gemm K
#define MQP 20096    // 157*128 padded nodes
#define KE 512       // padded edge-K (505 -> 512)
#define MEP 100096   // 782*128 padded edges

// d_out float offsets: h[25.6M], edge_core[50.5M], global_fea[1280], att[2M]
#define OUT_EC  25600000ull
#define OUT_GF  76100000ull
#define OUT_ATT 76101280ull

// workspace byte offsets
#define WS_HB   0ull                 // u16[MQP*KQ]
#define WS_ECB  51445760ull          // u16[MEP*KE]
#define WS_WQT  153944064ull         // u16[NQ*KQ]   (B^T for Q gemm)
#define WS_WMT  160497664ull         // u16[DN*KE]   (B^T for EC gemm)
#define WS_QB   161808384ull         // u16[MQP*NQ]  (node projections, bf16)
#define WS_EXPW 264699904ull         // f32[NEDGES*NH]
#define WS_P    272699904ull         // f32[NNODES*40]
#define WS_S    275899904ull         // f32[20]
#define WS_GF   275900160ull         // f32[1280]
#define WS_Y1   275905280ull         // f32[5120]
#define WS_Z    275925760ull         // f32[1280]
#define WS_GO   275930880ull         // f32[1280]
#define WS_ZERO_FLOATS 9024          // zero span from WS_S

typedef unsigned short u16;
typedef __attribute__((ext_vector_type(8))) short bf16x8;
typedef __attribute__((ext_vector_type(4))) float f32x4;
typedef __attribute__((ext_vector_type(4))) unsigned short us4;
typedef __attribute__((ext_vector_type(4))) float fl4;

__device__ __forceinline__ float bf2f(u16 u){ union{unsigned v; float f;} x; x.v = ((unsigned)u)<<16; return x.f; }
__device__ __forceinline__ u16 f2bf(float f){ union{float f; unsigned v;} x; x.f=f; unsigned r = x.v + 0x7FFFu + ((x.v>>16)&1u); return (u16)(r>>16); }

#define GLD16(gp, lp) __builtin_amdgcn_global_load_lds((const __attribute__((address_space(1))) void*)(gp), (__attribute__((address_space(3))) void*)(lp), 16, 0, 0)

__global__ void k_init(float* z){
  int i = blockIdx.x*blockDim.x + threadIdx.x;
  if (i < WS_ZERO_FLOATS) z[i] = 0.f;
}

// h -> bf16 padded [MQP][DN], and copy h -> out
__global__ void k_prep_h(const float* __restrict__ h, u16* __restrict__ hb, float* __restrict__ outh){
  const size_t total = (size_t)MQP*DN/4;
  const size_t lim = (size_t)NNODES*DN/4;
  size_t stride = (size_t)gridDim.x*blockDim.x;
  for (size_t i = (size_t)blockIdx.x*blockDim.x + threadIdx.x; i < total; i += stride){
    fl4 v = {0.f,0.f,0.f,0.f};
    if (i < lim){ v = *(const fl4*)(h + i*4); *(fl4*)(outh + i*4) = v; }
    us4 b; b[0]=f2bf(v[0]); b[1]=f2bf(v[1]); b[2]=f2bf(v[2]); b[3]=f2bf(v[3]);
    *(us4*)(hb + i*4) = b;
  }
}

// edge_core: copy to out + bf16 into padded [MEP][512] rows; separate pad zero-fill
__global__ void k_prep_ec(const float* __restrict__ ec, u16* __restrict__ ecb, float* __restrict__ outec){
  unsigned stride = gridDim.x*blockDim.x;
  unsigned tid = blockIdx.x*blockDim.x + threadIdx.x;
  const unsigned n = (unsigned)NEDGES*DE;
  for (unsigned s = tid; s < n; s += stride){
    float v = ec[s];
    outec[s] = v;
    unsigned e = s/DE, k = s - e*DE;
    ecb[((size_t)e<<9)+k] = f2bf(v);
  }
  const unsigned padA = (unsigned)NEDGES*7;
  const unsigned padB = (unsigned)(MEP-NEDGES)*512;
  for (unsigned i = tid; i < padA + padB; i += stride){
    size_t dst;
    if (i < padA){ unsigned e = i/7, c = i - e*7; dst = ((size_t)e<<9) + DE + c; }
    else { dst = ((size_t)NEDGES<<9) + (i - padA); }
    ecb[dst] = 0;
  }
}

// W_node top/bottom rows -> wqt[c][k] (transposed, bf16) via LDS tile
__global__ void k_prep_wq(const float* __restrict__ Wn, u16* __restrict__ wqt){
  __shared__ u16 tile[32][36];
  int bc = blockIdx.x % 80;   // c-tile (2560/32)
  int bk = blockIdx.x / 80;   // k-tile (1280/32)
  int c0 = bc*32, k0 = bk*32;
  int tr = threadIdx.x >> 3;
  int tc = (threadIdx.x & 7) * 4;
  int cc = c0 + tc;
  const float* src = (c0 < DN) ? (Wn + (size_t)(k0+tr)*DN + cc)
                               : (Wn + (size_t)(1785+k0+tr)*DN + (cc-DN));
  fl4 v = *(const fl4*)src;
  tile[tr][tc+0]=f2bf(v[0]); tile[tr][tc+1]=f2bf(v[1]); tile[tr][tc+2]=f2bf(v[2]); tile[tr][tc+3]=f2bf(v[3]);
  __syncthreads();
  int oc = threadIdx.x >> 3;
  int ok = (threadIdx.x & 7)*4;
  us4 o; o[0]=tile[ok+0][oc]; o[1]=tile[ok+1][oc]; o[2]=tile[ok+2][oc]; o[3]=tile[ok+3][oc];
  *(us4*)(wqt + (size_t)(c0+oc)*KQ + k0 + ok) = o;
}

// W_node mid rows -> wmt[c][kk] (transposed, k-padded to 512, bf16)
__global__ void k_prep_wm(const float* __restrict__ Wn, u16* __restrict__ wmt){
  __shared__ u16 tile[32][36];
  int bc = blockIdx.x % 40;   // c-tile (1280/32)
  int bk = blockIdx.x / 40;   // k-tile (512/32)
  int c0 = bc*32, k0 = bk*32;
  int tr = threadIdx.x >> 3;
  int tc = (threadIdx.x & 7) * 4;
  int kk = k0 + tr;
  fl4 v = {0.f,0.f,0.f,0.f};
  if (kk < DE) v = *(const fl4*)(Wn + (size_t)(DN+kk)*DN + c0 + tc);
  tile[tr][tc+0]=f2bf(v[0]); tile[tr][tc+1]=f2bf(v[1]); tile[tr][tc+2]=f2bf(v[2]); tile[tr][tc+3]=f2bf(v[3]);
  __syncthreads();
  int oc = threadIdx.x >> 3;
  int ok = (threadIdx.x & 7)*4;
  us4 o; o[0]=tile[ok+0][oc]; o[1]=tile[ok+1][oc]; o[2]=tile[ok+2][oc]; o[3]=tile[ok+3][oc];
  *(us4*)(wmt + (size_t)(c0+oc)*KE + k0 + ok) = o;
}

// P[n][c]: c<20 -> h.Wa_top col c ; c>=20 -> h.Wa_bot col c-20   (fp32)
__global__ void k_P(const float* __restrict__ h, const float* __restrict__ Wa, float* __restrict__ P){
  int i = blockIdx.x*blockDim.x + threadIdx.x;
  if (i >= NNODES*40) return;
  int n = i / 40, c = i % 40;
  const float* hr = h + (size_t)n*DN;
  const float* wcol = (c < NH) ? (Wa + c) : (Wa + (size_t)1785*NH + (c-NH));
  float acc = 0.f;
  for (int k=0;k<DN;k++) acc += hr[k]*wcol[(size_t)k*NH];
  P[i] = acc;
}

// per-edge logits -> expw, and S[h] = sum exp (no max-sub: relu'd logits >=0, small)
__global__ void k_w(const float* __restrict__ ec, const float* __restrict__ P,
                    const int* __restrict__ idx, const float* __restrict__ Wa,
                    const float* __restrict__ ba, float* __restrict__ expw, float* __restrict__ S){
  __shared__ float ssum[NH];
  int t = threadIdx.x;
  if (t < NH) ssum[t] = 0.f;
  __syncthreads();
  int i = blockIdx.x*blockDim.x + t;
  float ev = 0.f; int hh = 0;
  if (i < NEDGES*NH){
    int e = i / NH; hh = i % NH;
    int ii = idx[e], jj = idx[NEDGES+e];
    float acc = P[ii*40+hh] + P[jj*40+NH+hh] + ba[hh];
    const float* er = ec + (size_t)e*DE;
    const float* wc = Wa + (size_t)DN*NH + hh;
    for (int k=0;k<DE;k++) acc += er[k]*wc[(size_t)k*NH];
    float w = fmaxf(acc, 0.f)*0.125f;
    ev = expf(w);
    expw[i] = ev;
  }
  atomicAdd(&ssum[hh], ev);
  __syncthreads();
  if (t < NH) atomicAdd(&S[t], ssum[t]);
}

__global__ void k_att(const float* __restrict__ expw, const float* __restrict__ S, float* __restrict__ att){
  size_t stride = (size_t)gridDim.x*blockDim.x;
  for (size_t i = (size_t)blockIdx.x*blockDim.x + threadIdx.x; i < (size_t)NEDGES*NH; i += stride)
    att[i] = expw[i] / S[i % NH];
}

// 2-phase double-buffered bf16 MFMA GEMM, 128x128 tile, BK=32, 4 waves (2x2), B^T input.
// XOR chunk-swizzle (pre-swizzled global source, swizzled ds_read). XCD-bijective bid swizzle.
// EPI=0: store bf16 to Qb.  EPI=1: fused gather(Q)+bias+gelu+att-weighted column reduce -> gf.
template<int KSTEPS, int EPI>
__global__ __launch_bounds__(256, 3) void k_gemm(
    const u16* __restrict__ A, const u16* __restrict__ Bt, int K, int Ntiles,
    u16* __restrict__ Qb,
    const int* __restrict__ idx, const float* __restrict__ bnode,
    const float* __restrict__ att, float* __restrict__ gf)
{
  __shared__ u16 lsA[2][4096];
  __shared__ u16 lsB[2][4096];
  __shared__ float red[128];
  int t = threadIdx.x; int w = t>>6; int l = t&63;
  // bijective XCD swizzle (m204)
  int nwg = gridDim.x, orig = blockIdx.x;
  int q = nwg >> 3, r8 = nwg & 7, xcd = orig & 7, pos = orig >> 3;
  int bid = (xcd < r8 ? xcd*(q+1) : r8*(q+1) + (xcd-r8)*q) + pos;
  int mt = bid / Ntiles, nt = bid % Ntiles;
  size_t m0 = (size_t)mt*128; int n0 = nt*128;
  // staging: thread t stages row (t>>2) [and +64], 16B chunk swizzled by row&3
  int srow = t>>2;
  int schunk = (t&3) ^ (srow&3);
  const u16* gA = A + (m0 + (size_t)srow)*K + (schunk<<3);
  const u16* gB = Bt + ((size_t)n0 + srow)*K + (schunk<<3);
  size_t skip = (size_t)64*K;
  f32x4 acc[4][4];
  #pragma unroll
  for (int a=0;a<4;a++)
    #pragma unroll
    for (int b=0;b<4;b++) acc[a][b] = 0.f;
  int wm = w>>1, wn = w&1;
  int lrow = l&15;
  int rxor = ((l>>4) ^ (lrow&3)) << 3;   // u16 offset of swizzled 16B chunk

  // prologue: stage buffer 0
  GLD16(gA, &lsA[0][w*512]); GLD16(gA+skip, &lsA[0][2048 + w*512]);
  GLD16(gB, &lsB[0][w*512]); GLD16(gB+skip, &lsB[0][2048 + w*512]);
  gA += 32; gB += 32;
  __syncthreads();
  int cur = 0;
  for (int ks=0; ks<KSTEPS; ks++){
    if (ks+1 < KSTEPS){
      int nx = cur^1;
      GLD16(gA, &lsA[nx][w*512]); GLD16(gA+skip, &lsA[nx][2048 + w*512]);
      GLD16(gB, &lsB[nx][w*512]); GLD16(gB+skip, &lsB[nx][2048 + w*512]);
      gA += 32; gB += 32;
    }
    bf16x8 af[4], bfv[4];
    #pragma unroll
    for (int f=0; f<4; f++){
      af[f]  = *(const bf16x8*)(&lsA[cur][((wm*64 + f*16 + lrow)<<5) + rxor]);
      bfv[f] = *(const bf16x8*)(&lsB[cur][((wn*64 + f*16 + lrow)<<5) + rxor]);
    }
    #pragma unroll
    for (int fm=0; fm<4; fm++)
      #pragma unroll
      for (int fn=0; fn<4; fn++)
        acc[fm][fn] = __builtin_amdgcn_mfma_f32_16x16x32_bf16(af[fm], bfv[fn], acc[fm][fn], 0, 0, 0);
    __syncthreads();   // drains vmcnt (prefetch done) + all waves done reading lsX[cur]
    cur ^= 1;
  }
  int orow = wm*64 + ((l>>4)<<2);   // + fm*16 + r
  int ocol = wn*64 + lrow;          // + fn*16
  if (EPI == 0){
    #pragma unroll
    for (int fm=0; fm<4; fm++)
      #pragma unroll
      for (int fn=0; fn<4; fn++)
        #pragma unroll
        for (int r=0; r<4; r++)
          Qb[(m0 + orow + fm*16 + r)*(size_t)NQ + n0 + ocol + fn*16] = f2bf(acc[fm][fn][r]);
  } else {
    if (t < 128) red[t] = 0.f;
    __syncthreads();
    float csum[4] = {0.f,0.f,0.f,0.f};
    float bn4[4]; int hd4[4];
    #pragma unroll
    for (int fn=0; fn<4; fn++){ int col = n0 + ocol + fn*16; bn4[fn] = bnode[col]; hd4[fn] = col>>6; }
    #pragma unroll
    for (int fm=0; fm<4; fm++)
      #pragma unroll
      for (int r=0; r<4; r++){
        int e = (int)m0 + orow + fm*16 + r;
        if (e < NEDGES){
          int ii = idx[e], jj = idx[NEDGES+e];
          const u16* qi = Qb + (size_t)ii*NQ + n0 + ocol;
          const u16* qj = Qb + (size_t)jj*NQ + DN + n0 + ocol;
          #pragma unroll
          for (int fn=0; fn<4; fn++){
            float u = acc[fm][fn][r] + bf2f(qi[fn*16]) + bf2f(qj[fn*16]) + bn4[fn];
            float g = 0.5f*u*(1.f + erff(u*0.70710678118654752f));
            csum[fn] += att[(size_t)e*NH + hd4[fn]] * g;
          }
        }
      }
    #pragma unroll
    for (int fn=0; fn<4; fn++) atomicAdd(&red[ocol + fn*16], csum[fn]);
    __syncthreads();
    if (t < 128) atomicAdd(&gf[n0 + t], red[t]);
  }
}

// FF: y1pre += gf@W1 chunk (+b1 on kc0); relu applied when read in ff2
__global__ void k_ff1(const float* __restrict__ gf, const float* __restrict__ W1,
                      const float* __restrict__ b1, float* __restrict__ y1pre){
  __shared__ float sg[320];
  int jc = blockIdx.x % 20, kc = blockIdx.x / 20;
  int j = jc*256 + threadIdx.x;
  int k0 = kc*320;
  for (int i=threadIdx.x; i<320; i+=256) sg[i] = gf[k0+i];
  __syncthreads();
  float acc = (kc==0) ? b1[j] : 0.f;
  for (int k=0;k<320;k++) acc += sg[k]*W1[(size_t)(k0+k)*5120 + j];
  atomicAdd(&y1pre[j], acc);
}

__global__ void k_ff2(const float* __restrict__ y1pre, const float* __restrict__ W2,
                      const float* __restrict__ b2, float* __restrict__ z){
  __shared__ float sy[640];
  int dc = blockIdx.x % 5, kc = blockIdx.x / 5;
  int d = dc*256 + threadIdx.x;
  int k0 = kc*640;
  for (int i=threadIdx.x; i<640; i+=256) sy[i] = fmaxf(y1pre[k0+i], 0.f);
  __syncthreads();
  float acc = (kc==0) ? b2[d] : 0.f;
  for (int k=0;k<640;k++) acc += sy[k]*W2[(size_t)(k0+k)*1280 + d];
  atomicAdd(&z[d], acc);
}

__global__ void k_ff3(const float* __restrict__ z, const float* __restrict__ Wh, float* __restrict__ go){
  __shared__ float sz[320];
  int dc = blockIdx.x % 5, kc = blockIdx.x / 5;
  int d = dc*256 + threadIdx.x;
  int k0 = kc*320;
  for (int i=threadIdx.x; i<320; i+=256) sz[i] = z[k0+i];
  __syncthreads();
  float acc = 0.f;
  for (int k=0;k<320;k++) acc += sz[k]*Wh[(size_t)(k0+k)*1280 + d];
  atomicAdd(&go[d], acc);
}

__global__ void k_final(const float* __restrict__ go, float* __restrict__ outgf){
  int d = blockIdx.x*blockDim.x + threadIdx.x;
  if (d < 1280) outgf[d] = go[d];
}

extern "C" void kernel_launch(void* const* d_in, const int* in_sizes, int n_in,
                              void* d_out, int out_size, void* d_ws, size_t ws_size,
                              hipStream_t stream){
  const float* h   = (const float*)d_in[0];
  const float* ec  = (const float*)d_in[1];
  const int*   idx = (const int*)d_in[2];
  const float* Wa  = (const float*)d_in[3];
  const float* ba  = (const float*)d_in[4];
  const float* Wn  = (const float*)d_in[5];
  const float* bn  = (const float*)d_in[6];
  const float* W1  = (const float*)d_in[7];
  const float* b1  = (const float*)d_in[8];
  const float* W2  = (const float*)d_in[9];
  const float* b2  = (const float*)d_in[10];
  const float* Wh  = (const float*)d_in[11];
  float* out = (float*)d_out;
  char* ws = (char*)d_ws;
  u16* hb   = (u16*)(ws + WS_HB);
  u16* ecb  = (u16*)(ws + WS_ECB);
  u16* wqt  = (u16*)(ws + WS_WQT);
  u16* wmt  = (u16*)(ws + WS_WMT);
  u16* qb   = (u16*)(ws + WS_QB);
  float* expw = (float*)(ws + WS_EXPW);
  float* P    = (float*)(ws + WS_P);
  float* S    = (float*)(ws + WS_S);
  float* gfb  = (float*)(ws + WS_GF);
  float* y1   = (float*)(ws + WS_Y1);
  float* z    = (float*)(ws + WS_Z);
  float* go   = (float*)(ws + WS_GO);

  k_init<<<36,256,0,stream>>>(S);
  k_prep_h<<<2048,256,0,stream>>>(h, hb, out);
  k_prep_ec<<<3072,256,0,stream>>>(ec, ecb, out + OUT_EC);
  k_prep_wq<<<3200,256,0,stream>>>(Wn, wqt);
  k_prep_wm<<<640,256,0,stream>>>(Wn, wmt);
  k_P<<<3125,256,0,stream>>>(h, Wa, P);
  k_w<<<7813,256,0,stream>>>(ec, P, idx, Wa, ba, expw, S);
  k_att<<<2048,256,0,stream>>>(expw, S, out + OUT_ATT);
  k_gemm<40,0><<<157*20,256,0,stream>>>(hb, wqt, KQ, 20, qb, nullptr, nullptr, nullptr, nullptr);
  k_gemm<16,1><<<782*10,256,0,stream>>>(ecb, wmt, KE, 10, qb, idx, bn, out + OUT_ATT, gfb);
  k_ff1<<<80,256,0,stream>>>(gfb, W1, b1, y1);
  k_ff2<<<40,256,0,stream>>>(y1, W2, b2, z);
  k_ff3<<<20,256,0,stream>>>(z, Wh, go);
  k_final<<<5,256,0,stream>>>(go, out + OUT_GF);
}

// Round 5
// 1467.049 us; speedup vs baseline: 1.7237x; 1.2951x over previous
//
#include <hip/hip_runtime.h>
#include <math.h>

#define NNODES 20000
#define NEDGES 100000
#define DN 1280
#define DE 505
#define NH 20
#define NQ 2560      // Q gemm N (= 2*DN)
#define KQ 1280      // Q gemm K
#define MQP 20096    // 157*128 padded nodes
#define KE 512       // padded edge-K (505 -> 512)
#define MEP 100096   // 782*128 padded edges

// d_out float offsets: h[25.6M], edge_core[50.5M], global_fea[1280], att[2M]
#define OUT_EC  25600000ull
#define OUT_GF  76100000ull
#define OUT_ATT 76101280ull

// workspace byte offsets
#define WS_HB   0ull                 // u16[MQP*KQ]
#define WS_ECB  51445760ull          // u16[MEP*KE]
#define WS_WQT  153944064ull         // u16[NQ*KQ]   (B^T for Q gemm)
#define WS_WMT  160497664ull         // u16[DN*KE]   (B^T for EC gemm)
#define WS_QB   161808384ull         // u16[MQP*NQ]  (node projections, bf16)
// transient (inside Qb region; all consumed before Q-gemm writes Qb):
#define WS_EW   161808384ull         // f32[NEDGES*20]  (8.0 MB)
#define WS_WAT  (161808384ull + 16000000ull)  // u16[128*KQ] P-gemm B^T
#define WS_WET  (161808384ull + 17000000ull)  // u16[128*KE] EW-gemm B^T
#define WS_EXPW 264699904ull         // f32[NEDGES*NH]
#define WS_P    272699904ull         // f32[NNODES*40]
#define WS_S    275899904ull         // f32[20]
#define WS_GF   275900160ull         // f32[1280]
#define WS_Y1   275905280ull         // f32[5120]
#define WS_Z    275925760ull         // f32[1280]
#define WS_GO   275930880ull         // f32[1280]
#define WS_ZERO_FLOATS 9024          // zero span from WS_S

typedef unsigned short u16;
typedef __attribute__((ext_vector_type(8))) short bf16x8;
typedef __attribute__((ext_vector_type(4))) float f32x4;
typedef __attribute__((ext_vector_type(4))) unsigned short us4;
typedef __attribute__((ext_vector_type(4))) float fl4;

__device__ __forceinline__ float bf2f(u16 u){ union{unsigned v; float f;} x; x.v = ((unsigned)u)<<16; return x.f; }
__device__ __forceinline__ u16 f2bf(float f){ union{float f; unsigned v;} x; x.f=f; unsigned r = x.v + 0x7FFFu + ((x.v>>16)&1u); return (u16)(r>>16); }

#define GLD16(gp, lp) __builtin_amdgcn_global_load_lds((const __attribute__((address_space(1))) void*)(gp), (__attribute__((address_space(3))) void*)(lp), 16, 0, 0)

__global__ void k_init(float* z){
  int i = blockIdx.x*blockDim.x + threadIdx.x;
  if (i < WS_ZERO_FLOATS) z[i] = 0.f;
}

// h -> bf16 padded [MQP][DN], and copy h -> out
__global__ void k_prep_h(const float* __restrict__ h, u16* __restrict__ hb, float* __restrict__ outh){
  const size_t total = (size_t)MQP*DN/4;
  const size_t lim = (size_t)NNODES*DN/4;
  size_t stride = (size_t)gridDim.x*blockDim.x;
  for (size_t i = (size_t)blockIdx.x*blockDim.x + threadIdx.x; i < total; i += stride){
    fl4 v = {0.f,0.f,0.f,0.f};
    if (i < lim){ v = *(const fl4*)(h + i*4); *(fl4*)(outh + i*4) = v; }
    us4 b; b[0]=f2bf(v[0]); b[1]=f2bf(v[1]); b[2]=f2bf(v[2]); b[3]=f2bf(v[3]);
    *(us4*)(hb + i*4) = b;
  }
}

// edge_core: copy to out + bf16 into padded [MEP][512] rows; separate pad zero-fill
__global__ void k_prep_ec(const float* __restrict__ ec, u16* __restrict__ ecb, float* __restrict__ outec){
  unsigned stride = gridDim.x*blockDim.x;
  unsigned tid = blockIdx.x*blockDim.x + threadIdx.x;
  const unsigned n = (unsigned)NEDGES*DE;
  for (unsigned s = tid; s < n; s += stride){
    float v = ec[s];
    outec[s] = v;
    unsigned e = s/DE, k = s - e*DE;
    ecb[((size_t)e<<9)+k] = f2bf(v);
  }
  const unsigned padA = (unsigned)NEDGES*7;
  const unsigned padB = (unsigned)(MEP-NEDGES)*512;
  for (unsigned i = tid; i < padA + padB; i += stride){
    size_t dst;
    if (i < padA){ unsigned e = i/7, c = i - e*7; dst = ((size_t)e<<9) + DE + c; }
    else { dst = ((size_t)NEDGES<<9) + (i - padA); }
    ecb[dst] = 0;
  }
}

// W_node top/bottom rows -> wqt[c][k] (transposed, bf16) via LDS tile
__global__ void k_prep_wq(const float* __restrict__ Wn, u16* __restrict__ wqt){
  __shared__ u16 tile[32][36];
  int bc = blockIdx.x % 80;   // c-tile (2560/32)
  int bk = blockIdx.x / 80;   // k-tile (1280/32)
  int c0 = bc*32, k0 = bk*32;
  int tr = threadIdx.x >> 3;
  int tc = (threadIdx.x & 7) * 4;
  int cc = c0 + tc;
  const float* src = (c0 < DN) ? (Wn + (size_t)(k0+tr)*DN + cc)
                               : (Wn + (size_t)(1785+k0+tr)*DN + (cc-DN));
  fl4 v = *(const fl4*)src;
  tile[tr][tc+0]=f2bf(v[0]); tile[tr][tc+1]=f2bf(v[1]); tile[tr][tc+2]=f2bf(v[2]); tile[tr][tc+3]=f2bf(v[3]);
  __syncthreads();
  int oc = threadIdx.x >> 3;
  int ok = (threadIdx.x & 7)*4;
  us4 o; o[0]=tile[ok+0][oc]; o[1]=tile[ok+1][oc]; o[2]=tile[ok+2][oc]; o[3]=tile[ok+3][oc];
  *(us4*)(wqt + (size_t)(c0+oc)*KQ + k0 + ok) = o;
}

// W_node mid rows -> wmt[c][kk] (transposed, k-padded to 512, bf16)
__global__ void k_prep_wm(const float* __restrict__ Wn, u16* __restrict__ wmt){
  __shared__ u16 tile[32][36];
  int bc = blockIdx.x % 40;   // c-tile (1280/32)
  int bk = blockIdx.x / 40;   // k-tile (512/32)
  int c0 = bc*32, k0 = bk*32;
  int tr = threadIdx.x >> 3;
  int tc = (threadIdx.x & 7) * 4;
  int kk = k0 + tr;
  fl4 v = {0.f,0.f,0.f,0.f};
  if (kk < DE) v = *(const fl4*)(Wn + (size_t)(DN+kk)*DN + c0 + tc);
  tile[tr][tc+0]=f2bf(v[0]); tile[tr][tc+1]=f2bf(v[1]); tile[tr][tc+2]=f2bf(v[2]); tile[tr][tc+3]=f2bf(v[3]);
  __syncthreads();
  int oc = threadIdx.x >> 3;
  int ok = (threadIdx.x & 7)*4;
  us4 o; o[0]=tile[ok+0][oc]; o[1]=tile[ok+1][oc]; o[2]=tile[ok+2][oc]; o[3]=tile[ok+3][oc];
  *(us4*)(wmt + (size_t)(c0+oc)*KE + k0 + ok) = o;
}

// W_att node parts -> wat[c][k] bf16 [128][1280]: c<20: Wa_top col c; 20<=c<40: Wa_bot col c-20; else 0
__global__ void k_prep_wa(const float* __restrict__ Wa, u16* __restrict__ wat){
  int i = blockIdx.x*blockDim.x + threadIdx.x;
  if (i >= 128*KQ) return;
  int c = i / KQ, k = i - c*KQ;
  float v = 0.f;
  if (c < NH) v = Wa[(size_t)k*NH + c];
  else if (c < 2*NH) v = Wa[(size_t)(1785+k)*NH + (c-NH)];
  wat[i] = f2bf(v);
}

// W_att edge part -> wet[c][kk] bf16 [128][512]: c<20 && kk<505: Wa[(1280+kk)*20+c]; else 0
__global__ void k_prep_we(const float* __restrict__ Wa, u16* __restrict__ wet){
  int i = blockIdx.x*blockDim.x + threadIdx.x;
  if (i >= 128*KE) return;
  int c = i >> 9, kk = i & (KE-1);
  float v = (c < NH && kk < DE) ? Wa[(size_t)(DN+kk)*NH + c] : 0.f;
  wet[i] = f2bf(v);
}

// per-edge logits (from P gather + EW) -> expw, and S[h] = sum exp
__global__ void k_logit(const float* __restrict__ P, const float* __restrict__ EW,
                        const int* __restrict__ idx, const float* __restrict__ ba,
                        float* __restrict__ expw, float* __restrict__ S){
  __shared__ float ssum[NH];
  int t = threadIdx.x;
  if (t < NH) ssum[t] = 0.f;
  __syncthreads();
  int i = blockIdx.x*blockDim.x + t;
  float ev = 0.f; int hh = 0;
  if (i < NEDGES*NH){
    int e = i / NH; hh = i - e*NH;
    int ii = idx[e], jj = idx[NEDGES+e];
    float acc = P[ii*40+hh] + P[jj*40+NH+hh] + EW[i] + ba[hh];
    float w = fmaxf(acc, 0.f)*0.125f;
    ev = expf(w);
    expw[i] = ev;
  }
  atomicAdd(&ssum[hh], ev);
  __syncthreads();
  if (t < NH) atomicAdd(&S[t], ssum[t]);
}

__global__ void k_att(const float* __restrict__ expw, const float* __restrict__ S, float* __restrict__ att){
  size_t stride = (size_t)gridDim.x*blockDim.x;
  for (size_t i = (size_t)blockIdx.x*blockDim.x + threadIdx.x; i < (size_t)NEDGES*NH; i += stride)
    att[i] = expw[i] / S[i % NH];
}

// 2-phase double-buffered bf16 MFMA GEMM, 128x128 tile, BK=32, 4 waves (2x2), B^T input.
// Bank-conflict-free chunk swizzle: key = (row>>1)&3 (pre-swizzled global src + swizzled read).
// EPI=0: store bf16 to Qb.  EPI=1: fused gather(Q)+bias+gelu+att-weighted column reduce -> gf.
// EPI=2: store f32 cols<40 to P.  EPI=3: store f32 cols<20 to EW.
template<int KSTEPS, int EPI>
__global__ __launch_bounds__(256, 4) void k_gemm(
    const u16* __restrict__ A, const u16* __restrict__ Bt, int K, int Ntiles,
    u16* __restrict__ Qb,
    const int* __restrict__ idx, const float* __restrict__ bnode,
    const float* __restrict__ att, float* __restrict__ gf)
{
  __shared__ u16 lsA[2][4096];
  __shared__ u16 lsB[2][4096];
  __shared__ float red[128];
  int t = threadIdx.x; int w = t>>6; int l = t&63;
  // bijective XCD swizzle (m204)
  int nwg = gridDim.x, orig = blockIdx.x;
  int q = nwg >> 3, r8 = nwg & 7, xcd = orig & 7, pos = orig >> 3;
  int bid = (xcd < r8 ? xcd*(q+1) : r8*(q+1) + (xcd-r8)*q) + pos;
  int mt = bid / Ntiles, nt = bid % Ntiles;
  size_t m0 = (size_t)mt*128; int n0 = nt*128;
  // staging: thread t stages row (t>>2) [and +64], 16B chunk swizzled by (row>>1)&3
  int srow = t>>2;
  int schunk = (t&3) ^ ((srow>>1)&3);
  const u16* gA = A + (m0 + (size_t)srow)*K + (schunk<<3);
  const u16* gB = Bt + ((size_t)n0 + srow)*K + (schunk<<3);
  size_t skip = (size_t)64*K;
  f32x4 acc[4][4];
  #pragma unroll
  for (int a=0;a<4;a++)
    #pragma unroll
    for (int b=0;b<4;b++) acc[a][b] = 0.f;
  int wm = w>>1, wn = w&1;
  int lrow = l&15;
  int rxor = ((l>>4) ^ ((lrow>>1)&3)) << 3;   // u16 offset of swizzled 16B chunk

  // prologue: stage buffer 0
  GLD16(gA, &lsA[0][w*512]); GLD16(gA+skip, &lsA[0][2048 + w*512]);
  GLD16(gB, &lsB[0][w*512]); GLD16(gB+skip, &lsB[0][2048 + w*512]);
  gA += 32; gB += 32;
  __syncthreads();
  int cur = 0;
  for (int ks=0; ks<KSTEPS; ks++){
    if (ks+1 < KSTEPS){
      int nx = cur^1;
      GLD16(gA, &lsA[nx][w*512]); GLD16(gA+skip, &lsA[nx][2048 + w*512]);
      GLD16(gB, &lsB[nx][w*512]); GLD16(gB+skip, &lsB[nx][2048 + w*512]);
      gA += 32; gB += 32;
    }
    bf16x8 af[4], bfv[4];
    #pragma unroll
    for (int f=0; f<4; f++){
      af[f]  = *(const bf16x8*)(&lsA[cur][((wm*64 + f*16 + lrow)<<5) + rxor]);
      bfv[f] = *(const bf16x8*)(&lsB[cur][((wn*64 + f*16 + lrow)<<5) + rxor]);
    }
    #pragma unroll
    for (int fm=0; fm<4; fm++)
      #pragma unroll
      for (int fn=0; fn<4; fn++)
        acc[fm][fn] = __builtin_amdgcn_mfma_f32_16x16x32_bf16(af[fm], bfv[fn], acc[fm][fn], 0, 0, 0);
    __syncthreads();   // drains vmcnt (prefetch done) + all waves done reading lsX[cur]
    cur ^= 1;
  }
  int orow = wm*64 + ((l>>4)<<2);   // + fm*16 + r
  int ocol = wn*64 + lrow;          // + fn*16
  if (EPI == 0){
    #pragma unroll
    for (int fm=0; fm<4; fm++)
      #pragma unroll
      for (int fn=0; fn<4; fn++)
        #pragma unroll
        for (int r=0; r<4; r++)
          Qb[(m0 + orow + fm*16 + r)*(size_t)NQ + n0 + ocol + fn*16] = f2bf(acc[fm][fn][r]);
  } else if (EPI == 2){
    // P[node][40], cols 0..39 only
    #pragma unroll
    for (int fm=0; fm<4; fm++)
      #pragma unroll
      for (int fn=0; fn<4; fn++){
        int col = ocol + fn*16;
        if (col < 40){
          #pragma unroll
          for (int r=0; r<4; r++){
            size_t row = m0 + orow + fm*16 + r;
            if (row < NNODES) gf[row*40 + col] = acc[fm][fn][r];
          }
        }
      }
  } else if (EPI == 3){
    // EW[edge][20], cols 0..19 only
    #pragma unroll
    for (int fm=0; fm<4; fm++)
      #pragma unroll
      for (int fn=0; fn<4; fn++){
        int col = ocol + fn*16;
        if (col < NH){
          #pragma unroll
          for (int r=0; r<4; r++){
            size_t row = m0 + orow + fm*16 + r;
            if (row < NEDGES) gf[row*NH + col] = acc[fm][fn][r];
          }
        }
      }
  } else {
    if (t < 128) red[t] = 0.f;
    __syncthreads();
    float csum[4] = {0.f,0.f,0.f,0.f};
    float bn4[4]; int hd4[4];
    #pragma unroll
    for (int fn=0; fn<4; fn++){ int col = n0 + ocol + fn*16; bn4[fn] = bnode[col]; hd4[fn] = col>>6; }
    #pragma unroll
    for (int fm=0; fm<4; fm++)
      #pragma unroll
      for (int r=0; r<4; r++){
        int e = (int)m0 + orow + fm*16 + r;
        if (e < NEDGES){
          int ii = idx[e], jj = idx[NEDGES+e];
          const u16* qi = Qb + (size_t)ii*NQ + n0 + ocol;
          const u16* qj = Qb + (size_t)jj*NQ + DN + n0 + ocol;
          #pragma unroll
          for (int fn=0; fn<4; fn++){
            float u = acc[fm][fn][r] + bf2f(qi[fn*16]) + bf2f(qj[fn*16]) + bn4[fn];
            float g = 0.5f*u*(1.f + erff(u*0.70710678118654752f));
            csum[fn] += att[(size_t)e*NH + hd4[fn]] * g;
          }
        }
      }
    #pragma unroll
    for (int fn=0; fn<4; fn++) atomicAdd(&red[ocol + fn*16], csum[fn]);
    __syncthreads();
    if (t < 128) atomicAdd(&gf[n0 + t], red[t]);
  }
}

// FF: y1pre += gf@W1 chunk (+b1 on kc0); relu applied when read in ff2
__global__ void k_ff1(const float* __restrict__ gf, const float* __restrict__ W1,
                      const float* __restrict__ b1, float* __restrict__ y1pre){
  __shared__ float sg[320];
  int jc = blockIdx.x % 20, kc = blockIdx.x / 20;
  int j = jc*256 + threadIdx.x;
  int k0 = kc*320;
  for (int i=threadIdx.x; i<320; i+=256) sg[i] = gf[k0+i];
  __syncthreads();
  float acc = (kc==0) ? b1[j] : 0.f;
  for (int k=0;k<320;k++) acc += sg[k]*W1[(size_t)(k0+k)*5120 + j];
  atomicAdd(&y1pre[j], acc);
}

__global__ void k_ff2(const float* __restrict__ y1pre, const float* __restrict__ W2,
                      const float* __restrict__ b2, float* __restrict__ z){
  __shared__ float sy[640];
  int dc = blockIdx.x % 5, kc = blockIdx.x / 5;
  int d = dc*256 + threadIdx.x;
  int k0 = kc*640;
  for (int i=threadIdx.x; i<640; i+=256) sy[i] = fmaxf(y1pre[k0+i], 0.f);
  __syncthreads();
  float acc = (kc==0) ? b2[d] : 0.f;
  for (int k=0;k<640;k++) acc += sy[k]*W2[(size_t)(k0+k)*1280 + d];
  atomicAdd(&z[d], acc);
}

__global__ void k_ff3(const float* __restrict__ z, const float* __restrict__ Wh, float* __restrict__ go){
  __shared__ float sz[320];
  int dc = blockIdx.x % 5, kc = blockIdx.x / 5;
  int d = dc*256 + threadIdx.x;
  int k0 = kc*320;
  for (int i=threadIdx.x; i<320; i+=256) sz[i] = z[k0+i];
  __syncthreads();
  float acc = 0.f;
  for (int k=0;k<320;k++) acc += sz[k]*Wh[(size_t)(k0+k)*1280 + d];
  atomicAdd(&go[d], acc);
}

__global__ void k_final(const float* __restrict__ go, float* __restrict__ outgf){
  int d = blockIdx.x*blockDim.x + threadIdx.x;
  if (d < 1280) outgf[d] = go[d];
}

extern "C" void kernel_launch(void* const* d_in, const int* in_sizes, int n_in,
                              void* d_out, int out_size, void* d_ws, size_t ws_size,
                              hipStream_t stream){
  const float* h   = (const float*)d_in[0];
  const float* ec  = (const float*)d_in[1];
  const int*   idx = (const int*)d_in[2];
  const float* Wa  = (const float*)d_in[3];
  const float* ba  = (const float*)d_in[4];
  const float* Wn  = (const float*)d_in[5];
  const float* bn  = (const float*)d_in[6];
  const float* W1  = (const float*)d_in[7];
  const float* b1  = (const float*)d_in[8];
  const float* W2  = (const float*)d_in[9];
  const float* b2  = (const float*)d_in[10];
  const float* Wh  = (const float*)d_in[11];
  float* out = (float*)d_out;
  char* ws = (char*)d_ws;
  u16* hb   = (u16*)(ws + WS_HB);
  u16* ecb  = (u16*)(ws + WS_ECB);
  u16* wqt  = (u16*)(ws + WS_WQT);
  u16* wmt  = (u16*)(ws + WS_WMT);
  u16* qb   = (u16*)(ws + WS_QB);
  u16* wat  = (u16*)(ws + WS_WAT);
  u16* wet  = (u16*)(ws + WS_WET);
  float* EW   = (float*)(ws + WS_EW);
  float* expw = (float*)(ws + WS_EXPW);
  float* P    = (float*)(ws + WS_P);
  float* S    = (float*)(ws + WS_S);
  float* gfb  = (float*)(ws + WS_GF);
  float* y1   = (float*)(ws + WS_Y1);
  float* z    = (float*)(ws + WS_Z);
  float* go   = (float*)(ws + WS_GO);

  k_init<<<36,256,0,stream>>>(S);
  k_prep_h<<<2048,256,0,stream>>>(h, hb, out);
  k_prep_ec<<<3072,256,0,stream>>>(ec, ecb, out + OUT_EC);
  k_prep_wq<<<3200,256,0,stream>>>(Wn, wqt);
  k_prep_wm<<<640,256,0,stream>>>(Wn, wmt);
  k_prep_wa<<<640,256,0,stream>>>(Wa, wat);
  k_prep_we<<<256,256,0,stream>>>(Wa, wet);
  // P = h @ [Wa_top|Wa_bot]  (f32 out, cols<40)
  k_gemm<40,2><<<157,256,0,stream>>>(hb, wat, KQ, 1, nullptr, nullptr, nullptr, nullptr, P);
  // EW = ec @ Wa_mid  (f32 out, cols<20)
  k_gemm<16,3><<<782,256,0,stream>>>(ecb, wet, KE, 1, nullptr, nullptr, nullptr, nullptr, EW);
  k_logit<<<7813,256,0,stream>>>(P, EW, idx, ba, expw, S);
  k_att<<<2048,256,0,stream>>>(expw, S, out + OUT_ATT);
  k_gemm<40,0><<<157*20,256,0,stream>>>(hb, wqt, KQ, 20, qb, nullptr, nullptr, nullptr, nullptr);
  k_gemm<16,1><<<782*10,256,0,stream>>>(ecb, wmt, KE, 10, qb, idx, bn, out + OUT_ATT, gfb);
  k_ff1<<<80,256,0,stream>>>(gfb, W1, b1, y1);
  k_ff2<<<40,256,0,stream>>>(y1, W2, b2, z);
  k_ff3<<<20,256,0,stream>>>(z, Wh, go);
  k_final<<<5,256,0,stream>>>(go, out + OUT_GF);
}